// Round 3
// baseline (19.267 us; speedup 1.0000x reference)
//
#include <hip/hip_runtime.h>

// Problem constants
#define B_    16
#define T_    512
#define C_    8
#define TOUT_ 481          // T - KSZ + 1
#define EPS_  1e-8f
#define LXS   9            // padded row stride for lx (conflict-free p loads)

// out[b,t,k2] = pp[t,k2] + min_s (kk[s,k2] + sum_j p[t,k2,j]*kn'[s,k2,j])
// with kn' = -2 * normalized kernel, kk = ||kn||^2.
__global__ __launch_bounds__(256) void lsd_fused(
    const float* __restrict__ x, const float* __restrict__ kern,
    float* __restrict__ out) {
  __shared__ float lk[16384];    // kn' layout [s][c][k2][4]  (c = j>>2)
  __shared__ float lkk[2048];    // kk[s][k2]
  __shared__ float lx[63 * LXS]; // normalized x rows t0..t0+62
  __shared__ float red[64];      // x-stat cross-wave scratch
  __shared__ float cstat[16];    // cmean[8], crstd[8]

  int tid = threadIdx.x;
  int l   = tid & 63;            // lane
  int v   = tid >> 6;            // wave
  int b   = blockIdx.x >> 4;
  int t0  = (blockIdx.x & 15) << 5;

  // ---------- Phase A: kernel normalization, 16 s per wave ----------
  // lane l loads source chunk (k2 = l&31, c = l>>5) -> float4 idx 2*k2 + c.
  // Permuted-but-dense within 1KB => fully coalesced; LDS write is lane-
  // contiguous b128 (conflict-free), read side [s][c][k2] is also
  // conflict-free (lanes 0..31 contiguous, 32..63 broadcast).
  const float4* kern4 = reinterpret_cast<const float4*>(kern);
  int lp = 2 * (l & 31) + (l >> 5);
  float4 kv[16];
  #pragma unroll
  for (int w = 0; w < 16; ++w)
    kv[w] = kern4[(4 * w + v) * 64 + lp];

  // issue x loads early (for Phase B stats)
  const float4* x4 = reinterpret_cast<const float4*>(x) + b * 1024;
  float4 xv[4];
  #pragma unroll
  for (int u = 0; u < 4; ++u) xv[u] = x4[tid + 256 * u];

  float4* lk4 = reinterpret_cast<float4*>(lk);
  #pragma unroll
  for (int w = 0; w < 16; ++w) {
    int s = 4 * w + v;
    float4 f = kv[w];
    float sm = f.x + f.y + f.z + f.w;
    float sq = f.x * f.x;
    sq = fmaf(f.y, f.y, sq); sq = fmaf(f.z, f.z, sq); sq = fmaf(f.w, f.w, sq);
    #pragma unroll
    for (int m = 1; m < 64; m <<= 1) {
      sm += __shfl_xor(sm, m, 64);
      sq += __shfl_xor(sq, m, 64);
    }
    float mean = sm * (1.0f / 256.0f);
    float var  = fmaxf(sq * (1.0f / 256.0f) - mean * mean, 0.0f);
    float rstd = 1.0f / (sqrtf(var) + EPS_);
    float a  = -2.0f * rstd;
    float bb =  2.0f * mean * rstd;   // kn' = -2*(v-mean)*rstd = v*a + bb
    float4 kn;
    kn.x = fmaf(f.x, a, bb); kn.y = fmaf(f.y, a, bb);
    kn.z = fmaf(f.z, a, bb); kn.w = fmaf(f.w, a, bb);
    float q = kn.x * kn.x;
    q = fmaf(kn.y, kn.y, q); q = fmaf(kn.z, kn.z, q); q = fmaf(kn.w, kn.w, q);
    lk4[s * 64 + l] = kn;             // conflict-free b128 write
    q += __shfl_xor(q, 32, 64);       // combine c=0/1 halves (same k2)
    if (l < 32) lkk[s * 32 + l] = q * 0.25f;  // kk = sum vn^2 = sum kn'^2 / 4
  }

  // ---------- Phase B: x channel stats ----------
  float4 s4 = {0,0,0,0}, q4 = {0,0,0,0};
  #pragma unroll
  for (int u = 0; u < 4; ++u) {
    s4.x += xv[u].x; s4.y += xv[u].y; s4.z += xv[u].z; s4.w += xv[u].w;
    q4.x = fmaf(xv[u].x, xv[u].x, q4.x); q4.y = fmaf(xv[u].y, xv[u].y, q4.y);
    q4.z = fmaf(xv[u].z, xv[u].z, q4.z); q4.w = fmaf(xv[u].w, xv[u].w, q4.w);
  }
  #pragma unroll
  for (int m = 2; m <= 32; m <<= 1) {   // reduce within wave over same parity
    s4.x += __shfl_xor(s4.x, m, 64); s4.y += __shfl_xor(s4.y, m, 64);
    s4.z += __shfl_xor(s4.z, m, 64); s4.w += __shfl_xor(s4.w, m, 64);
    q4.x += __shfl_xor(q4.x, m, 64); q4.y += __shfl_xor(q4.y, m, 64);
    q4.z += __shfl_xor(q4.z, m, 64); q4.w += __shfl_xor(q4.w, m, 64);
  }
  if (l < 2) {                          // l = parity g (0: ch0-3, 1: ch4-7)
    int base = v * 16 + l * 8;
    red[base + 0] = s4.x; red[base + 1] = s4.y;
    red[base + 2] = s4.z; red[base + 3] = s4.w;
    red[base + 4] = q4.x; red[base + 5] = q4.y;
    red[base + 6] = q4.z; red[base + 7] = q4.w;
  }
  __syncthreads();
  if (tid < 8) {
    int g = tid >> 2, cp = tid & 3;
    float sm = 0.f, sq = 0.f;
    #pragma unroll
    for (int w = 0; w < 4; ++w) {
      sm += red[w * 16 + g * 8 + cp];
      sq += red[w * 16 + g * 8 + 4 + cp];
    }
    float mean = sm * (1.0f / 512.0f);
    float var  = fmaxf(sq * (1.0f / 512.0f) - mean * mean, 0.0f);
    cstat[tid]     = mean;
    cstat[8 + tid] = 1.0f / (sqrtf(var) + EPS_);
  }
  __syncthreads();

  // stage normalized rows t0..t0+62 (float4 global loads, L1/L2-hot)
  if (tid < 126) {
    int gi4 = t0 * 2 + tid;            // float4 index within x[b]
    float4 f = (gi4 < 1024) ? x4[gi4] : make_float4(0.f, 0.f, 0.f, 0.f);
    int row = tid >> 1, cb = (tid & 1) * 4;
    float* dst = &lx[row * LXS + cb];
    dst[0] = (f.x - cstat[cb + 0]) * cstat[8 + cb + 0];
    dst[1] = (f.y - cstat[cb + 1]) * cstat[8 + cb + 1];
    dst[2] = (f.z - cstat[cb + 2]) * cstat[8 + cb + 2];
    dst[3] = (f.w - cstat[cb + 3]) * cstat[8 + cb + 3];
  }
  __syncthreads();   // covers lk/lkk (Phase A) + lx

  // ---------- Main loop ----------
  int k2  = tid & 31;
  int tq  = tid >> 5;        // 0..7
  int off = (k2 & 3) * 8;
  int cch = k2 >> 2;

  float p[4][8], pp[4], mn[4];
  #pragma unroll
  for (int r = 0; r < 4; ++r) {
    int trel = tq + 8 * r;
    float acc = 0.0f;
    #pragma unroll
    for (int j = 0; j < 8; ++j) {
      float vv = lx[(trel + off + j) * LXS + cch];
      p[r][j] = vv;
      acc = fmaf(vv, vv, acc);
    }
    pp[r] = acc;
    mn[r] = 3.0e38f;
  }

  #pragma unroll 4
  for (int s = 0; s < 64; ++s) {
    float4 kf0 = lk4[s * 64 + k2];        // j 0..3, coalesced b128
    float4 kf1 = lk4[s * 64 + 32 + k2];   // j 4..7
    float kkv  = lkk[s * 32 + k2];
    float kn8[8] = {kf0.x, kf0.y, kf0.z, kf0.w, kf1.x, kf1.y, kf1.z, kf1.w};
    #pragma unroll
    for (int r = 0; r < 4; ++r) {
      float d = kkv;                      // kk - 2*dot via kn' = -2*kn
      #pragma unroll
      for (int j = 0; j < 8; ++j) d = fmaf(p[r][j], kn8[j], d);
      mn[r] = fminf(mn[r], d);
    }
  }

  #pragma unroll
  for (int r = 0; r < 4; ++r) {
    int t = t0 + tq + 8 * r;
    if (t < TOUT_) out[(b * TOUT_ + t) * 32 + k2] = pp[r] + mn[r];
  }
}

extern "C" void kernel_launch(void* const* d_in, const int* in_sizes, int n_in,
                              void* d_out, int out_size, void* d_ws, size_t ws_size,
                              hipStream_t stream) {
  const float* x    = (const float*)d_in[0];
  const float* kern = (const float*)d_in[1];
  float* out = (float*)d_out;
  lsd_fused<<<256, 256, 0, stream>>>(x, kern, out);
}

// Round 4
// 18.503 us; speedup vs baseline: 1.0413x; 1.0413x over previous
//
#include <hip/hip_runtime.h>

#define TOUT_ 481
#define EPS_  1e-8f

typedef __attribute__((ext_vector_type(8))) short bf16x8;
typedef __attribute__((ext_vector_type(4))) float f32x4;

__device__ __forceinline__ unsigned short f2bf(float f) {
  union { float f; unsigned u; } a; a.f = f;
  unsigned r = a.u + 0x7fffu + ((a.u >> 16) & 1u);
  return (unsigned short)(r >> 16);
}
__device__ __forceinline__ float bf2f(unsigned short h) {
  union { unsigned u; float f; } a; a.u = ((unsigned)h) << 16;
  return a.f;
}

// Grid: blockIdx = b*16 + c*2 + th. Block = 256 thr (4 waves).
// out[b,t,k2=4c+o] = pp(t,o) + min_s( kk[s,o] + sum_u A[t,u]*B[u,(s,o)] )
//   A[t,u] = bf16(xn[b, t+u, c])          (sliding window, K=32)
//   B[u,(s,o)] = bf16(-2*kn[s,4c+o,j]) for u = 8o+j, else 0
// kk folded into MFMA C-in (per-col broadcast).
__global__ __launch_bounds__(256) void lsd_mfma(
    const float* __restrict__ x, const float* __restrict__ kern,
    float* __restrict__ out) {
  __shared__ unsigned short Bls[8192];   // [so=s*4+o][u] bf16, XOR-swizzled
  __shared__ float kkls[256];            // kk[so]
  __shared__ unsigned short lxb[544];    // bf16 xn channel c (zero-padded)
  __shared__ unsigned int   lxp[520];    // lxp[m] = (lxb[m], lxb[m+1])
  __shared__ float wsum[512];            // sliding sum of squares, window 8
  __shared__ float red[64];
  __shared__ float cstat[16];

  int tid  = threadIdx.x;
  int lane = tid & 63;
  int wv   = tid >> 6;
  int b    = blockIdx.x >> 4;
  int c    = (blockIdx.x >> 1) & 7;
  int th   = blockIdx.x & 1;

  // ---- zero B matrix (16 KB) ----
  {
    int4* bz = reinterpret_cast<int4*>(Bls);
    #pragma unroll
    for (int i = 0; i < 4; ++i) bz[tid + 256 * i] = make_int4(0, 0, 0, 0);
  }

  // ---- global loads (early issue) ----
  int s = tid >> 2, q = tid & 3;
  const float4* kern4 = reinterpret_cast<const float4*>(kern);
  float4 kv[16];
  #pragma unroll
  for (int u = 0; u < 16; ++u) kv[u] = kern4[s * 64 + q * 16 + u];

  const float4* x4 = reinterpret_cast<const float4*>(x) + b * 1024;
  float4 xv[4];
  #pragma unroll
  for (int u = 0; u < 4; ++u) xv[u] = x4[tid + 256 * u];

  // ---- kernel stats (4 threads per s, parallel over all 64 s) ----
  float ksum = 0.f, ksq = 0.f;
  #pragma unroll
  for (int u = 0; u < 16; ++u) {
    ksum += kv[u].x + kv[u].y + kv[u].z + kv[u].w;
    ksq = fmaf(kv[u].x, kv[u].x, ksq); ksq = fmaf(kv[u].y, kv[u].y, ksq);
    ksq = fmaf(kv[u].z, kv[u].z, ksq); ksq = fmaf(kv[u].w, kv[u].w, ksq);
  }
  ksum += __shfl_xor(ksum, 1, 64); ksq += __shfl_xor(ksq, 1, 64);
  ksum += __shfl_xor(ksum, 2, 64); ksq += __shfl_xor(ksq, 2, 64);
  float kmean = ksum * (1.0f / 256.0f);
  float kvar  = fmaxf(ksq * (1.0f / 256.0f) - kmean * kmean, 0.0f);
  float krstd = 1.0f / (sqrtf(kvar) + EPS_);

  __syncthreads();   // B zeros complete

  // ---- scatter normalized kernel (only thread with matching quarter) ----
  if (q == (c >> 1)) {
    int ub = (c & 1) * 8;
    float kka[4] = {0.f, 0.f, 0.f, 0.f};
    char* braw = reinterpret_cast<char*>(Bls);
    #pragma unroll
    for (int up = 0; up < 8; ++up) {
      float4 f = kv[ub + up];
      float vals[4] = {f.x, f.y, f.z, f.w};
      #pragma unroll
      for (int cc = 0; cc < 4; ++cc) {
        int uu = (ub + up) * 4 + cc;     // 0..31 (c even) / 32..63 (c odd)
        int o  = (uu >> 3) & 3;
        int j  = uu & 7;
        float vn = (vals[cc] - kmean) * krstd;
        float vq = bf2f(f2bf(vn));       // quantized value (for kk consistency)
        kka[o] = fmaf(vq, vq, kka[o]);
        unsigned short nb = f2bf(-2.0f * vn);   // == bits of -2*vq
        int byte = (s * 4 + o) * 64 + 16 * o + 2 * j;
        *reinterpret_cast<unsigned short*>(braw + (byte ^ ((s & 7) << 4))) = nb;
      }
    }
    #pragma unroll
    for (int o = 0; o < 4; ++o) kkls[s * 4 + o] = kka[o];
  }

  // ---- x channel stats (R2-verified pattern) ----
  float4 s4v = {0, 0, 0, 0}, q4v = {0, 0, 0, 0};
  #pragma unroll
  for (int u = 0; u < 4; ++u) {
    s4v.x += xv[u].x; s4v.y += xv[u].y; s4v.z += xv[u].z; s4v.w += xv[u].w;
    q4v.x = fmaf(xv[u].x, xv[u].x, q4v.x); q4v.y = fmaf(xv[u].y, xv[u].y, q4v.y);
    q4v.z = fmaf(xv[u].z, xv[u].z, q4v.z); q4v.w = fmaf(xv[u].w, xv[u].w, q4v.w);
  }
  #pragma unroll
  for (int m = 2; m <= 32; m <<= 1) {
    s4v.x += __shfl_xor(s4v.x, m, 64); s4v.y += __shfl_xor(s4v.y, m, 64);
    s4v.z += __shfl_xor(s4v.z, m, 64); s4v.w += __shfl_xor(s4v.w, m, 64);
    q4v.x += __shfl_xor(q4v.x, m, 64); q4v.y += __shfl_xor(q4v.y, m, 64);
    q4v.z += __shfl_xor(q4v.z, m, 64); q4v.w += __shfl_xor(q4v.w, m, 64);
  }
  if (lane < 2) {
    int base = wv * 16 + lane * 8;
    red[base + 0] = s4v.x; red[base + 1] = s4v.y;
    red[base + 2] = s4v.z; red[base + 3] = s4v.w;
    red[base + 4] = q4v.x; red[base + 5] = q4v.y;
    red[base + 6] = q4v.z; red[base + 7] = q4v.w;
  }
  __syncthreads();   // red ready; B scatter done
  if (tid < 8) {
    int g = tid >> 2, cp = tid & 3;
    float sm = 0.f, sq = 0.f;
    #pragma unroll
    for (int w = 0; w < 4; ++w) {
      sm += red[w * 16 + g * 8 + cp];
      sq += red[w * 16 + g * 8 + 4 + cp];
    }
    float mean = sm * (1.0f / 512.0f);
    float var  = fmaxf(sq * (1.0f / 512.0f) - mean * mean, 0.0f);
    cstat[tid]     = mean;
    cstat[8 + tid] = 1.0f / (sqrtf(var) + EPS_);
  }
  __syncthreads();

  // ---- build bf16 normalized channel from registers (no reload) ----
  if ((tid & 1) == (c >> 2)) {
    float cm = cstat[c], cr = cstat[8 + c];
    #pragma unroll
    for (int u = 0; u < 4; ++u) {
      int t = (tid >> 1) + 128 * u;
      float4 f = xv[u];
      float val = (c & 2) ? ((c & 1) ? f.w : f.z) : ((c & 1) ? f.y : f.x);
      lxb[t] = f2bf((val - cm) * cr);
    }
  }
  if (tid < 32) lxb[512 + tid] = 0;
  __syncthreads();

  // ---- pair table (alignment-safe A loads) + sliding sum of squares ----
  for (int i = tid; i < 520; i += 256)
    lxp[i] = (unsigned)lxb[i] | ((unsigned)lxb[i + 1] << 16);
  for (int m = tid; m < 512; m += 256) {
    float acc = 0.f;
    #pragma unroll
    for (int j = 0; j < 8; ++j) { float v = bf2f(lxb[m + j]); acc = fmaf(v, v, acc); }
    wsum[m] = acc;
  }
  __syncthreads();

  // ---- load B fragments + kk into registers (held across all t-tiles) ----
  int l15 = lane & 15, kch = lane >> 4;
  bf16x8 Bf[16];
  float  kkv[16];
  const char* braw = reinterpret_cast<const char*>(Bls);
  #pragma unroll
  for (int g = 0; g < 16; ++g) {
    int so = g * 16 + l15;
    int addr = (so * 64 + kch * 16) ^ (((so >> 2) & 7) << 4);
    Bf[g]  = *reinterpret_cast<const bf16x8*>(braw + addr);
    kkv[g] = kkls[so];
  }

  // ---- main loop: 16 MFMA + 64 fmin per 16-row t-tile ----
  int NT = th ? 15 : 16;
  int la = l15 + 8 * kch;     // 0..39: A element offset = row + k-chunk*8
  for (int gt = wv; gt < NT; gt += 4) {
    int t0 = th * 248 + gt * 16;
    int p  = t0 + la;
    union { unsigned ui[4]; bf16x8 v; } au;
    au.ui[0] = lxp[p];     au.ui[1] = lxp[p + 2];
    au.ui[2] = lxp[p + 4]; au.ui[3] = lxp[p + 6];

    f32x4 mn = {3.0e38f, 3.0e38f, 3.0e38f, 3.0e38f};
    #pragma unroll
    for (int g = 0; g < 16; ++g) {
      f32x4 cin;
      cin[0] = kkv[g]; cin[1] = kkv[g]; cin[2] = kkv[g]; cin[3] = kkv[g];
      f32x4 d = __builtin_amdgcn_mfma_f32_16x16x32_bf16(au.v, Bf[g], cin, 0, 0, 0);
      mn[0] = fminf(mn[0], d[0]); mn[1] = fminf(mn[1], d[1]);
      mn[2] = fminf(mn[2], d[2]); mn[3] = fminf(mn[3], d[3]);
    }
    // reduce over s&3 (lane bits 2,3 of the col index)
    #pragma unroll
    for (int r = 0; r < 4; ++r) {
      mn[r] = fminf(mn[r], __shfl_xor(mn[r], 4, 64));
      mn[r] = fminf(mn[r], __shfl_xor(mn[r], 8, 64));
    }
    int o = lane & 3;
    float ma = (lane & 4) ? mn[1] : mn[0];
    float mb = (lane & 4) ? mn[3] : mn[2];
    float mv = (lane & 8) ? mb : ma;
    int t = t0 + (lane >> 4) * 4 + ((lane >> 2) & 3);
    if (t < TOUT_)
      out[(b * TOUT_ + t) * 32 + c * 4 + o] = wsum[t + 8 * o] + mv;
  }
}

extern "C" void kernel_launch(void* const* d_in, const int* in_sizes, int n_in,
                              void* d_out, int out_size, void* d_ws, size_t ws_size,
                              hipStream_t stream) {
  const float* x    = (const float*)d_in[0];
  const float* kern = (const float*)d_in[1];
  float* out = (float*)d_out;
  lsd_mfma<<<256, 256, 0, stream>>>(x, kern, out);
}

// Round 5
// 13.399 us; speedup vs baseline: 1.4379x; 1.3809x over previous
//
#include <hip/hip_runtime.h>

#define TOUT_ 481
#define EPS_  1e-8f

typedef __attribute__((ext_vector_type(8))) short bf16x8;
typedef __attribute__((ext_vector_type(4))) float f32x4;

__device__ __forceinline__ unsigned short f2bf(float f) {
  union { float f; unsigned u; } a; a.f = f;
  unsigned r = a.u + 0x7fffu + ((a.u >> 16) & 1u);
  return (unsigned short)(r >> 16);
}
__device__ __forceinline__ float bf2f(unsigned short h) {
  union { unsigned u; float f; } a; a.u = ((unsigned)h) << 16;
  return a.f;
}

// Grid: blockIdx = b*16 + c*2 + th. Block = 256 thr (4 waves).
// out[b,t,k2=4c+o] = pp(t,o) + min_s( kk[s,o] + sum_u A[t,u]*B[u,(s,o)] )
//   A[t,u] = bf16(xn[b, t+u, c]) (sliding window, K=32)
//   B[u,(so=s*4+o)] = bf16(-2*kn[s,4c+o,j]) for u = 8o+j, else 0
// kk folded into MFMA C-in (per-col broadcast). Main loop verified in R4.
__global__ __launch_bounds__(256) void lsd_mfma2(
    const float* __restrict__ x, const float* __restrict__ kern,
    float* __restrict__ out) {
  __shared__ alignas(16) unsigned short Bls[2048];  // [so][j]: nonzero 8 bf16
  __shared__ float kkls[256];            // kk[so]
  __shared__ unsigned short lxb[544];    // bf16 xn channel c (zero-padded)
  __shared__ unsigned int   lxp[520];    // lxp[m] = (lxb[m], lxb[m+1])
  __shared__ float wsum[512];            // sliding sum of squares, window 8
  __shared__ float red[64];
  __shared__ float cstat[16];

  int tid  = threadIdx.x;
  int lane = tid & 63;
  int wv   = tid >> 6;
  int b    = blockIdx.x >> 4;
  int c    = (blockIdx.x >> 1) & 7;
  int th   = blockIdx.x & 1;

  // ---- global loads (early issue) ----
  int s = tid >> 2, q = tid & 3;
  const float4* kern4 = reinterpret_cast<const float4*>(kern);
  float4 kv[16];
  #pragma unroll
  for (int u = 0; u < 16; ++u) kv[u] = kern4[s * 64 + q * 16 + u];

  const float4* x4 = reinterpret_cast<const float4*>(x) + b * 1024;
  float4 xv[4];
  #pragma unroll
  for (int u = 0; u < 4; ++u) xv[u] = x4[tid + 256 * u];

  int k2 = 4 * c + q;                    // this thread's owned column data
  float4 kb0 = kern4[s * 64 + k2 * 2];
  float4 kb1 = kern4[s * 64 + k2 * 2 + 1];

  // ---- kernel stats (4 threads per s; owner's s == stats s) ----
  float ksum = 0.f, ksq = 0.f;
  #pragma unroll
  for (int u = 0; u < 16; ++u) {
    ksum += kv[u].x + kv[u].y + kv[u].z + kv[u].w;
    ksq = fmaf(kv[u].x, kv[u].x, ksq); ksq = fmaf(kv[u].y, kv[u].y, ksq);
    ksq = fmaf(kv[u].z, kv[u].z, ksq); ksq = fmaf(kv[u].w, kv[u].w, ksq);
  }
  ksum += __shfl_xor(ksum, 1, 64); ksq += __shfl_xor(ksq, 1, 64);
  ksum += __shfl_xor(ksum, 2, 64); ksq += __shfl_xor(ksq, 2, 64);
  float kmean = ksum * (1.0f / 256.0f);
  float kvar  = fmaxf(ksq * (1.0f / 256.0f) - kmean * kmean, 0.0f);
  float krstd = 1.0f / (sqrtf(kvar) + EPS_);

  // ---- B build: thread owns so = tid = 4s+q; stats already in regs ----
  {
    float vv[8] = {kb0.x, kb0.y, kb0.z, kb0.w, kb1.x, kb1.y, kb1.z, kb1.w};
    union { unsigned u[4]; bf16x8 v; } bw;
    float kk = 0.f;
    #pragma unroll
    for (int jj = 0; jj < 4; ++jj) {
      float vn0 = (vv[2 * jj]     - kmean) * krstd;
      float vn1 = (vv[2 * jj + 1] - kmean) * krstd;
      unsigned short n0 = f2bf(-2.0f * vn0);   // == bits of -2*quantized(vn0)
      unsigned short n1 = f2bf(-2.0f * vn1);
      float vq0 = bf2f(f2bf(vn0));
      float vq1 = bf2f(f2bf(vn1));
      kk = fmaf(vq0, vq0, kk);
      kk = fmaf(vq1, vq1, kk);
      bw.u[jj] = (unsigned)n0 | ((unsigned)n1 << 16);
    }
    *reinterpret_cast<bf16x8*>(&Bls[tid * 8]) = bw.v;   // conflict-free b128
    kkls[tid] = kk;
  }

  // ---- x channel stats (R2/R4-verified pattern) ----
  float4 s4v = {0, 0, 0, 0}, q4v = {0, 0, 0, 0};
  #pragma unroll
  for (int u = 0; u < 4; ++u) {
    s4v.x += xv[u].x; s4v.y += xv[u].y; s4v.z += xv[u].z; s4v.w += xv[u].w;
    q4v.x = fmaf(xv[u].x, xv[u].x, q4v.x); q4v.y = fmaf(xv[u].y, xv[u].y, q4v.y);
    q4v.z = fmaf(xv[u].z, xv[u].z, q4v.z); q4v.w = fmaf(xv[u].w, xv[u].w, q4v.w);
  }
  #pragma unroll
  for (int m = 2; m <= 32; m <<= 1) {
    s4v.x += __shfl_xor(s4v.x, m, 64); s4v.y += __shfl_xor(s4v.y, m, 64);
    s4v.z += __shfl_xor(s4v.z, m, 64); s4v.w += __shfl_xor(s4v.w, m, 64);
    q4v.x += __shfl_xor(q4v.x, m, 64); q4v.y += __shfl_xor(q4v.y, m, 64);
    q4v.z += __shfl_xor(q4v.z, m, 64); q4v.w += __shfl_xor(q4v.w, m, 64);
  }
  if (lane < 2) {
    int base = wv * 16 + lane * 8;
    red[base + 0] = s4v.x; red[base + 1] = s4v.y;
    red[base + 2] = s4v.z; red[base + 3] = s4v.w;
    red[base + 4] = q4v.x; red[base + 5] = q4v.y;
    red[base + 6] = q4v.z; red[base + 7] = q4v.w;
  }
  __syncthreads();                       // sync1: red (Bls/kkls also covered)
  if (tid < 8) {
    int g = tid >> 2, cp = tid & 3;
    float sm = 0.f, sq = 0.f;
    #pragma unroll
    for (int w = 0; w < 4; ++w) {
      sm += red[w * 16 + g * 8 + cp];
      sq += red[w * 16 + g * 8 + 4 + cp];
    }
    float mean = sm * (1.0f / 512.0f);
    float var  = fmaxf(sq * (1.0f / 512.0f) - mean * mean, 0.0f);
    cstat[tid]     = mean;
    cstat[8 + tid] = 1.0f / (sqrtf(var) + EPS_);
  }
  __syncthreads();                       // sync2: cstat

  // ---- bf16 normalized channel from registers (R4-verified) ----
  if ((tid & 1) == (c >> 2)) {
    float cm = cstat[c], cr = cstat[8 + c];
    #pragma unroll
    for (int u = 0; u < 4; ++u) {
      int t = (tid >> 1) + 128 * u;
      float4 f = xv[u];
      float val = (c & 2) ? ((c & 1) ? f.w : f.z) : ((c & 1) ? f.y : f.x);
      lxb[t] = f2bf((val - cm) * cr);
    }
  }
  if (tid < 32) lxb[512 + tid] = 0;
  __syncthreads();                       // sync3: lxb

  // ---- B fragments + prebuilt C-in (Bls/kkls visible since sync1) ----
  int l15 = lane & 15, kch = lane >> 4;
  bool match = (kch == (l15 & 3));
  bf16x8 Bf[16];
  f32x4  cin[16];
  #pragma unroll
  for (int g = 0; g < 16; ++g) {
    int so = g * 16 + l15;
    bf16x8 z = {0, 0, 0, 0, 0, 0, 0, 0};
    Bf[g] = match ? *reinterpret_cast<const bf16x8*>(&Bls[so * 8]) : z;
    float kkv = kkls[so];
    cin[g][0] = kkv; cin[g][1] = kkv; cin[g][2] = kkv; cin[g][3] = kkv;
  }

  // ---- pair table + sliding sum of squares ----
  for (int i = tid; i < 520; i += 256)
    lxp[i] = (unsigned)lxb[i] | ((unsigned)lxb[i + 1] << 16);
  for (int m = tid; m < 512; m += 256) {
    float acc = 0.f;
    #pragma unroll
    for (int j = 0; j < 8; ++j) { float v = bf2f(lxb[m + j]); acc = fmaf(v, v, acc); }
    wsum[m] = acc;
  }
  __syncthreads();                       // sync4: lxp/wsum

  // ---- main loop (R4-verified): 16 MFMA + mins per 16-row t-tile ----
  int NT = th ? 15 : 16;
  int la = l15 + 8 * kch;                // A element offset = row + k-chunk*8
  for (int gt = wv; gt < NT; gt += 4) {
    int t0 = th * 248 + gt * 16;
    int p  = t0 + la;
    union { unsigned ui[4]; bf16x8 v; } au;
    au.ui[0] = lxp[p];     au.ui[1] = lxp[p + 2];
    au.ui[2] = lxp[p + 4]; au.ui[3] = lxp[p + 6];

    f32x4 mn = {3.0e38f, 3.0e38f, 3.0e38f, 3.0e38f};
    #pragma unroll
    for (int g = 0; g < 16; ++g) {
      f32x4 d = __builtin_amdgcn_mfma_f32_16x16x32_bf16(au.v, Bf[g], cin[g], 0, 0, 0);
      mn[0] = fminf(mn[0], d[0]); mn[1] = fminf(mn[1], d[1]);
      mn[2] = fminf(mn[2], d[2]); mn[3] = fminf(mn[3], d[3]);
    }
    #pragma unroll
    for (int r = 0; r < 4; ++r) {
      mn[r] = fminf(mn[r], __shfl_xor(mn[r], 4, 64));
      mn[r] = fminf(mn[r], __shfl_xor(mn[r], 8, 64));
    }
    int o = lane & 3;
    float ma = (lane & 4) ? mn[1] : mn[0];
    float mb = (lane & 4) ? mn[3] : mn[2];
    float mv = (lane & 8) ? mb : ma;
    int t = t0 + (lane >> 4) * 4 + ((lane >> 2) & 3);
    if (t < TOUT_)
      out[(b * TOUT_ + t) * 32 + c * 4 + o] = wsum[t + 8 * o] + mv;
  }
}

extern "C" void kernel_launch(void* const* d_in, const int* in_sizes, int n_in,
                              void* d_out, int out_size, void* d_ws, size_t ws_size,
                              hipStream_t stream) {
  const float* x    = (const float*)d_in[0];
  const float* kern = (const float*)d_in[1];
  float* out = (float*)d_out;
  lsd_mfma2<<<256, 256, 0, stream>>>(x, kern, out);
}